// Round 18
// baseline (545.289 us; speedup 1.0000x reference)
//
#include <hip/hip_runtime.h>
#include <math.h>

// ---------------------------------------------------------------------------
// MS-SSIM + MSE loss, (16,3,512,512) f32, 5 pyramid levels.
// R18: L0 gets a dual-stream kernel (ILP instead of TLP): full-width 512
// rows in LDS (no column strips/halo), each thread owns cols tid and
// tid+256 with two independent 4-field FIR chains -> 2 dep-chains per
// wave hide each other's LDS latency. ~112 VGPR, fits (256,4) budget.
// L1..L4 = R13's exact proven kernel + grids (best small-level total).
// HARD RULE (R6/R11/R15/R17): launch_bounds min-waves>4 collapses VGPR
// budget (8->32, 6->40) -> scratch -> 2-6x regression. NEVER raise it.
// Spill tripwire: WRITE_SIZE@L0 dispatch must stay ~25 MB.
// ---------------------------------------------------------------------------

#define NPLANES 48

struct GaussW { float g[11]; };

typedef float v2f __attribute__((ext_vector_type(2)));

// ws float offsets: pyramids + per-BLOCK partial areas
#define PYR2_OFF  4177920
#define P_L0      8355840   // 768 pairs
#define P_L1      8357376   // 768 pairs
#define P_L2      8358912   // 384 pairs
#define P_L3      8359680   // 96 pairs
#define P_L4      8359872   // 36 pairs
#define P_MSE     8359944   // 768 singles

#define C1F 1.0e-4f
#define C2F 9.0e-4f

// ---------------------------------------------------------------------------
// L0 kernel: W=512, BH=32, 1 plane/block, 2 cols/thread, 3-slot ring.
__global__ __launch_bounds__(256, 4) void ssim_l0(
    const float* __restrict__ x1, const float* __restrict__ x2, GaussW gw,
    float* __restrict__ partials, float* __restrict__ msep,
    float* __restrict__ d1, float* __restrict__ d2)
{
  constexpr int W = 512, Ho = 502, BH = 32, W2 = 256;
  constexpr int STRIDE = 524;  // 512 cols + 10 zero-pad + 2 align

  __shared__ v2f vbuf[3][STRIDE];
  __shared__ float red[3][4];

  const int tid = threadIdx.x;
  const int by = blockIdx.x;        // band 0..15
  const int plane = blockIdx.y;     // 0..47
  const int gr0 = BH * by;
  const int ROWS = ((W - gr0) < (BH + 10)) ? (W - gr0) : (BH + 10);
  const int c0 = tid, c1 = tid + 256;
  const size_t pb = (size_t)plane * W * W;

  // zero the pad columns once; staging never writes them -> stay zero
  if (tid < 12) {
    vbuf[0][512 + tid] = (v2f){0.f, 0.f};
    vbuf[1][512 + tid] = (v2f){0.f, 0.f};
    vbuf[2][512 + tid] = (v2f){0.f, 0.f};
  }

  // two independent 4-field FIRs (f* = stream0, h* = stream1)
  float f1[11], f2[11], f3[11], f4[11];
  float h1[11], h2[11], h3[11], h4[11];
#pragma unroll
  for (int j = 0; j < 11; ++j) {
    f1[j] = 0.f; f2[j] = 0.f; f3[j] = 0.f; f4[j] = 0.f;
    h1[j] = 0.f; h2[j] = 0.f; h3[j] = 0.f; h4[j] = 0.f;
  }

  float mse_acc = 0.f, ssim_acc = 0.f, cs_acc = 0.f;

  // ---- prologue: row 0 (MSE over all 512 cols rides here) ----
  {
    size_t ro = pb + (size_t)gr0 * W;
    float a0 = x1[ro + c0], b0 = x2[ro + c0];
    float a1 = x1[ro + c1], b1 = x2[ro + c1];
    float d0 = a0 - b0, d1_ = a1 - b1;
    mse_acc = fmaf(d0, d0, d1_ * d1_);
    vbuf[0][c0] = (v2f){a0, b0};
    vbuf[0][c1] = (v2f){a1, b1};
  }
  __syncthreads();

  int cur = 0;
  for (int rr = 0; rr < ROWS; ++rr) {
    int nxt = cur + 1; if (nxt == 3) nxt = 0;
    int prv = cur - 1; if (prv < 0) prv = 2;
    const bool have = (rr + 1) < ROWS;  // uniform

    // issue next row's loads early (4 dwords/thread, coalesced halves)
    float a0 = 0.f, b0 = 0.f, a1 = 0.f, b1 = 0.f;
    if (have) {
      size_t ro = pb + (size_t)(gr0 + rr + 1) * W;
      a0 = x1[ro + c0]; b0 = x2[ro + c0];
      a1 = x1[ro + c1]; b1 = x2[ro + c1];
    }

    // ---- H-pass: two interleaved independent 11-tap windows ----
    const v2f* r0 = &vbuf[cur][c0];
    const v2f* r1 = &vbuf[cur][c1];
    float s1 = 0.f, s2 = 0.f, s3 = 0.f, s4 = 0.f;
    float t1 = 0.f, t2 = 0.f, t3 = 0.f, t4 = 0.f;
#pragma unroll
    for (int k = 0; k < 11; ++k) {
      float w = gw.g[k];
      {
        v2f ab = r0[k];
        float wa = w * ab.x, wb = w * ab.y;
        s1 += wa; s2 += wb;
        s3 = fmaf(wa, ab.y, s3);
        s4 = fmaf(wa, ab.x, s4);
        s4 = fmaf(wb, ab.y, s4);
      }
      {
        v2f ab = r1[k];
        float wa = w * ab.x, wb = w * ab.y;
        t1 += wa; t2 += wb;
        t3 = fmaf(wa, ab.y, t3);
        t4 = fmaf(wa, ab.x, t4);
        t4 = fmaf(wb, ab.y, t4);
      }
    }

    // ---- V-pass: two independent shift-accumulate chains ----
#pragma unroll
    for (int j = 10; j >= 1; --j) {
      f1[j] = fmaf(gw.g[j], s1, f1[j - 1]);
      f2[j] = fmaf(gw.g[j], s2, f2[j - 1]);
      f3[j] = fmaf(gw.g[j], s3, f3[j - 1]);
      f4[j] = fmaf(gw.g[j], s4, f4[j - 1]);
      h1[j] = fmaf(gw.g[j], t1, h1[j - 1]);
      h2[j] = fmaf(gw.g[j], t2, h2[j - 1]);
      h3[j] = fmaf(gw.g[j], t3, h3[j - 1]);
      h4[j] = fmaf(gw.g[j], t4, h4[j - 1]);
    }
    f1[0] = gw.g[0] * s1; f2[0] = gw.g[0] * s2;
    f3[0] = gw.g[0] * s3; f4[0] = gw.g[0] * s4;
    h1[0] = gw.g[0] * t1; h2[0] = gw.g[0] * t2;
    h3[0] = gw.g[0] * t3; h4[0] = gw.g[0] * t4;

    // ---- emit SSIM/CS (stream0 always valid; stream1 if c1 < Ho) ----
    if (rr >= 10) {
      {
        float m1 = f1[10], m2 = f2[10], e12 = f3[10], esq = f4[10];
        float m12 = m1 * m2;
        float msq = fmaf(m1, m1, m2 * m2);
        float v1 = 2.f * (e12 - m12) + C2F;
        float vv2 = (esq - msq) + C2F;
        float csv = v1 * __builtin_amdgcn_rcpf(vv2);
        cs_acc += csv;
        ssim_acc += csv * (2.f * m12 + C1F) *
                    __builtin_amdgcn_rcpf(msq + C1F);
      }
      if (tid < 246) {
        float m1 = h1[10], m2 = h2[10], e12 = h3[10], esq = h4[10];
        float m12 = m1 * m2;
        float msq = fmaf(m1, m1, m2 * m2);
        float v1 = 2.f * (e12 - m12) + C2F;
        float vv2 = (esq - msq) + C2F;
        float csv = v1 * __builtin_amdgcn_rcpf(vv2);
        cs_acc += csv;
        ssim_acc += csv * (2.f * m12 + C1F) *
                    __builtin_amdgcn_rcpf(msq + C1F);
      }
    }

    // ---- fused 2x2 avgpool: all 256 threads, one pool col each ----
    if ((rr & 1) && rr < BH) {
      v2f x0 = vbuf[prv][2 * tid], x1v = vbuf[prv][2 * tid + 1];
      v2f y0 = vbuf[cur][2 * tid], y1v = vbuf[cur][2 * tid + 1];
      int orow = (gr0 >> 1) + (rr >> 1);
      size_t ob = (size_t)plane * W2 * W2 + (size_t)orow * W2 + tid;
      d1[ob] = 0.25f * ((x0.x + x1v.x) + (y0.x + y1v.x));
      d2[ob] = 0.25f * ((x0.y + x1v.y) + (y0.y + y1v.y));
    }

    // ---- stage next row, barrier ----
    if (have) {
      if (rr + 1 < BH) {
        float d0 = a0 - b0, d1_ = a1 - b1;
        mse_acc = fmaf(d0, d0, mse_acc);
        mse_acc = fmaf(d1_, d1_, mse_acc);
      }
      vbuf[nxt][c0] = (v2f){a0, b0};
      vbuf[nxt][c1] = (v2f){a1, b1};
      __syncthreads();
    }
    cur = nxt;
  }

  // ---- block reduce (ssim, cs, mse) ----
#pragma unroll
  for (int off = 32; off; off >>= 1) {
    ssim_acc += __shfl_down(ssim_acc, off);
    cs_acc += __shfl_down(cs_acc, off);
    mse_acc += __shfl_down(mse_acc, off);
  }
  int wave = tid >> 6, lane = tid & 63;
  if (lane == 0) {
    red[0][wave] = ssim_acc;
    red[1][wave] = cs_acc;
    red[2][wave] = mse_acc;
  }
  __syncthreads();
  if (tid == 0) {
    float s = 0.f, cc = 0.f, m = 0.f;
#pragma unroll
    for (int i = 0; i < 4; ++i) { s += red[0][i]; cc += red[1][i]; m += red[2][i]; }
    int bi = blockIdx.y * 16 + blockIdx.x;
    partials[2 * bi] = s;
    partials[2 * bi + 1] = cc;
    msep[bi] = m;
  }
}

// ---------------------------------------------------------------------------
// R13's proven kernel for L1..L4 (5-field FIR, 3-slot ring, per-row barrier).
template <int LOGW, int BH, int DO_POOL>
__global__ __launch_bounds__(256, 4) void ssim_band(
    const float* __restrict__ x1, const float* __restrict__ x2, GaussW gw,
    float* __restrict__ partials,
    float* __restrict__ d1, float* __restrict__ d2)
{
  constexpr int W = 1 << LOGW;
  constexpr int Ho = W - 10;
  constexpr int LOGWB = (LOGW > 8) ? 8 : LOGW;
  constexpr int WB = 1 << LOGWB;
  constexpr int P = 256 >> LOGWB;
  constexpr int STRIDE = WB + 12;
  constexpr int W2 = W >> 1;

  __shared__ v2f vbuf[3][P][STRIDE];
  __shared__ float red[2][4];

  const int tid = threadIdx.x;
  const int p = tid >> LOGWB;
  const int col = tid & (WB - 1);
  const int bx = blockIdx.x, by = blockIdx.y, bz = blockIdx.z;
  const int gcol = bx * WB + col;
  const int plane = bz * P + p;
  const size_t pb = (size_t)plane * W * W;
  const float* q1 = x1 + pb + gcol;
  const float* q2 = x2 + pb + gcol;
  const int gr0 = BH * by;
  const int ROWS = ((W - gr0) < (BH + 10)) ? (W - gr0) : (BH + 10);
  const bool xtra = (bx * WB + WB + col) < W;

  float acc0[11], acc1[11], acc2[11], acc3[11], acc4[11];
#pragma unroll
  for (int j = 0; j < 11; ++j) {
    acc0[j] = 0.f; acc1[j] = 0.f; acc2[j] = 0.f; acc3[j] = 0.f; acc4[j] = 0.f;
  }

  float ssim_acc = 0.f, cs_acc = 0.f;

  {
    size_t ro = (size_t)gr0 * W;
    float a = q1[ro], b = q2[ro];
    float ae = 0.f, be = 0.f;
    if (col < 12 && xtra) { ae = q1[ro + WB]; be = q2[ro + WB]; }
    vbuf[0][p][col] = (v2f){a, b};
    if (col < 12) vbuf[0][p][WB + col] = (v2f){ae, be};
  }
  __syncthreads();

  int cur = 0;
  for (int rr = 0; rr < ROWS; ++rr) {
    int nxt = cur + 1; if (nxt == 3) nxt = 0;
    int prv = cur - 1; if (prv < 0) prv = 2;
    const bool have = (rr + 1) < ROWS;

    float a = 0.f, b = 0.f, ae = 0.f, be = 0.f;
    if (have) {
      size_t ro = (size_t)(gr0 + rr + 1) * W;
      a = q1[ro]; b = q2[ro];
      if (col < 12 && xtra) { ae = q1[ro + WB]; be = q2[ro + WB]; }
    }

    const v2f* r = &vbuf[cur][p][col];
    float s1 = 0.f, s2 = 0.f, s11 = 0.f, s22 = 0.f, s12 = 0.f;
#pragma unroll
    for (int k = 0; k < 11; ++k) {
      v2f ab = r[k];
      float av = ab.x, bv = ab.y, w = gw.g[k];
      float wa = w * av, wb = w * bv;
      s1 += wa; s2 += wb;
      s11 = fmaf(wa, av, s11);
      s22 = fmaf(wb, bv, s22);
      s12 = fmaf(wa, bv, s12);
    }

#pragma unroll
    for (int j = 10; j >= 1; --j) {
      acc0[j] = fmaf(gw.g[j], s1, acc0[j - 1]);
      acc1[j] = fmaf(gw.g[j], s2, acc1[j - 1]);
      acc2[j] = fmaf(gw.g[j], s11, acc2[j - 1]);
      acc3[j] = fmaf(gw.g[j], s22, acc3[j - 1]);
      acc4[j] = fmaf(gw.g[j], s12, acc4[j - 1]);
    }
    acc0[0] = gw.g[0] * s1;
    acc1[0] = gw.g[0] * s2;
    acc2[0] = gw.g[0] * s11;
    acc3[0] = gw.g[0] * s22;
    acc4[0] = gw.g[0] * s12;

    if (rr >= 10 && gcol < Ho) {
      float m1 = acc0[10], m2 = acc1[10];
      float m1sq = m1 * m1, m2sq = m2 * m2, m12 = m1 * m2;
      float v1 = 2.f * (acc4[10] - m12) + C2F;
      float v2 = (acc2[10] - m1sq) + (acc3[10] - m2sq) + C2F;
      float csv = v1 * __builtin_amdgcn_rcpf(v2);
      cs_acc += csv;
      ssim_acc += csv * (2.f * m12 + C1F) *
                  __builtin_amdgcn_rcpf(m1sq + m2sq + C1F);
    }

    if (DO_POOL && (rr & 1) && rr < BH && col < (WB / 2)) {
      v2f x0 = vbuf[prv][p][2 * col], x1v = vbuf[prv][p][2 * col + 1];
      v2f y0 = vbuf[cur][p][2 * col], y1v = vbuf[cur][p][2 * col + 1];
      int orow = (gr0 >> 1) + (rr >> 1);
      size_t ob = (size_t)plane * W2 * W2 + (size_t)orow * W2 + bx * (WB / 2) + col;
      d1[ob] = 0.25f * ((x0.x + x1v.x) + (y0.x + y1v.x));
      d2[ob] = 0.25f * ((x0.y + x1v.y) + (y0.y + y1v.y));
    }

    if (have) {
      vbuf[nxt][p][col] = (v2f){a, b};
      if (col < 12) vbuf[nxt][p][WB + col] = (v2f){ae, be};
      __syncthreads();
    }
    cur = nxt;
  }

#pragma unroll
  for (int off = 32; off; off >>= 1) {
    ssim_acc += __shfl_down(ssim_acc, off);
    cs_acc += __shfl_down(cs_acc, off);
  }
  int wave = tid >> 6, lane = tid & 63;
  if (lane == 0) {
    red[0][wave] = ssim_acc;
    red[1][wave] = cs_acc;
  }
  __syncthreads();
  if (tid == 0) {
    float s = 0.f, cc = 0.f;
#pragma unroll
    for (int i = 0; i < 4; ++i) { s += red[0][i]; cc += red[1][i]; }
    int bi = (bz * gridDim.y + by) * gridDim.x + bx;
    partials[2 * bi] = s;
    partials[2 * bi + 1] = cc;
  }
}

// ---------------------------------------------------------------------------
__global__ __launch_bounds__(256) void final_kernel(
    const float* __restrict__ ws, float* __restrict__ out)
{
  __shared__ double sred[2][4];
  __shared__ double fin[11];  // ssim[5], cs[5], mse
  const int tid = threadIdx.x;
  const int offs[5] = {P_L0, P_L1, P_L2, P_L3, P_L4};
  const int cnts[5] = {768, 768, 384, 96, 36};

  for (int l = 0; l < 5; ++l) {
    double s0 = 0.0, s1 = 0.0;
    for (int i = tid; i < cnts[l]; i += 256) {
      s0 += (double)ws[offs[l] + 2 * i];
      s1 += (double)ws[offs[l] + 2 * i + 1];
    }
#pragma unroll
    for (int off = 32; off; off >>= 1) {
      s0 += __shfl_down(s0, off);
      s1 += __shfl_down(s1, off);
    }
    if ((tid & 63) == 0) { sred[0][tid >> 6] = s0; sred[1][tid >> 6] = s1; }
    __syncthreads();
    if (tid == 0) {
      double aa = 0.0, bb = 0.0;
      for (int i = 0; i < 4; ++i) { aa += sred[0][i]; bb += sred[1][i]; }
      fin[l] = aa;
      fin[5 + l] = bb;
    }
    __syncthreads();
  }

  {
    double s0 = 0.0;
    for (int i = tid; i < 768; i += 256) s0 += (double)ws[P_MSE + i];
#pragma unroll
    for (int off = 32; off; off >>= 1) s0 += __shfl_down(s0, off);
    if ((tid & 63) == 0) sred[0][tid >> 6] = s0;
    __syncthreads();
    if (tid == 0) {
      double aa = 0.0;
      for (int i = 0; i < 4; ++i) aa += sred[0][i];
      fin[10] = aa;
    }
    __syncthreads();
  }

  if (tid == 0) {
    const double wts[5] = {0.0448, 0.2856, 0.3001, 0.2363, 0.1333};
    const double dims[5] = {502.0, 246.0, 118.0, 54.0, 22.0};
    double mssim[5], mcs[5];
    for (int l = 0; l < 5; ++l) {
      double n = 48.0 * dims[l] * dims[l];
      mssim[l] = fin[l] / n;
      mcs[l] = fin[5 + l] / n;
    }
    // literal pytorch_msssim translation: prod(pow1[:-1] * pow2[-1])
    double p2last = pow(mssim[4], wts[4]);
    double prod = 1.0;
    for (int i = 0; i < 4; ++i) prod *= pow(mcs[i], wts[i]) * p2last;
    double msssim = prod;
    double mse = fin[10] / 12582912.0;
    out[0] = (float)(mse - msssim + 1.0);
    out[1] = (float)msssim;
  }
}

// ---------------------------------------------------------------------------
extern "C" void kernel_launch(void* const* d_in, const int* in_sizes, int n_in,
                              void* d_out, int out_size, void* d_ws, size_t ws_size,
                              hipStream_t stream)
{
  const float* rec = (const float*)d_in[0];   // reconst
  const float* orig = (const float*)d_in[1];  // original
  float* ws = (float*)d_ws;
  float* out = (float*)d_out;

  GaussW gw;
  {
    double g[11], s = 0.0;
    for (int i = 0; i < 11; ++i) {
      double x = (double)i - 5.0;
      g[i] = exp(-(x * x) / 4.5);
      s += g[i];
    }
    for (int i = 0; i < 11; ++i) gw.g[i] = (float)(g[i] / s);
  }

  // pyramid pointers
  float* A1 = ws + 0;
  float* A2 = ws + 3145728;
  float* A3 = ws + 3932160;
  float* A4 = ws + 4128768;
  float* B1 = ws + PYR2_OFF;
  float* B2 = ws + PYR2_OFF + 3145728;
  float* B3 = ws + PYR2_OFF + 3932160;
  float* B4 = ws + PYR2_OFF + 4128768;

  // L0: dual-stream full-width kernel; grid = (band, plane)
  ssim_l0<<<dim3(16, 48), 256, 0, stream>>>(
      orig, rec, gw, ws + P_L0, ws + P_MSE, A1, B1);    // 768 blocks

  // L1..L4: R13's proven kernel + grids
  ssim_band<8, 16, 1><<<dim3(1, 16, 48), 256, 0, stream>>>(
      A1, B1, gw, ws + P_L1, A2, B2);                   // 768 blocks
  ssim_band<7, 8, 1><<<dim3(1, 16, 24), 256, 0, stream>>>(
      A2, B2, gw, ws + P_L2, A3, B3);                   // 384 blocks
  ssim_band<6, 8, 1><<<dim3(1, 8, 12), 256, 0, stream>>>(
      A3, B3, gw, ws + P_L3, A4, B4);                   // 96 blocks
  ssim_band<5, 4, 0><<<dim3(1, 6, 6), 256, 0, stream>>>(
      A4, B4, gw, ws + P_L4, nullptr, nullptr);         // 36 blocks

  final_kernel<<<dim3(1), dim3(256), 0, stream>>>(ws, out);
}

// Round 19
// 151.366 us; speedup vs baseline: 3.6024x; 3.6024x over previous
//
#include <hip/hip_runtime.h>
#include <math.h>

// ---------------------------------------------------------------------------
// MS-SSIM + MSE loss, (16,3,512,512) f32, 5 pyramid levels.
// R19: two-kernel pipeline.
//  K0  = R14's proven L0 kernel (86us): merged 4-field FIR, 2 rows/barrier,
//        4-slot v2f ring, MSE + pool->A1/B1 fused. Grid (2,16,48).
//  K1  = ssim_rest: L1..L4 FUSED in one launch (1284 blocks). Each level
//        pools its input ON THE FLY from A1/B1 (PP=0..3: 1x1/2x2/4x4/8x8
//        mean) -- mathematically equal to iterated 2x2 pooling. No A2..A4
//        buffers, no serial level dependencies, no launch gaps; A1 set
//        (25 MB) stays L2-resident. R13's proven 5-field body per level.
//  Register lore (R6/R11/R15/R17/R18): allocator caps this family at ~64
//  VGPR; never exceed one FIR of state per thread; launch_bounds stays
//  (256,4). Spill tripwire: WRITE_SIZE@L0 ~25 MB.
// ---------------------------------------------------------------------------

#define NPLANES 48

struct GaussW { float g[11]; };

typedef float v2f __attribute__((ext_vector_type(2)));

// ws float offsets: pyramids (only L1 used now) + per-BLOCK partial areas
#define PYR2_OFF  4177920
#define P_L0      8355840   // 1536 pairs
#define P_L1      8358912   // 768 pairs
#define P_L2      8360448   // 384 pairs
#define P_L3      8361216   // 96 pairs
#define P_L4      8361408   // 36 pairs
#define P_MSE     8361480   // 1536 singles

#define C1F 1.0e-4f
#define C2F 9.0e-4f

// ---------------------------------------------------------------------------
// K0: L0 kernel (R14 exact). W=512, BH=32, col strips of 256 w/ halo.
__global__ __launch_bounds__(256, 4) void ssim_l0(
    const float* __restrict__ x1, const float* __restrict__ x2, GaussW gw,
    float* __restrict__ partials, float* __restrict__ msep,
    float* __restrict__ d1, float* __restrict__ d2)
{
  constexpr int W = 512, Ho = 502, BH = 32, WB = 256, STRIDE = WB + 12;
  constexpr int W2 = 256;

  __shared__ v2f vbuf[4][STRIDE];
  __shared__ float red[3][4];

  const int tid = threadIdx.x;
  const int col = tid;
  const int bx = blockIdx.x, by = blockIdx.y, bz = blockIdx.z;
  const int gcol = bx * WB + col;
  const int plane = bz;
  const size_t pb = (size_t)plane * W * W;
  const float* q1 = x1 + pb + gcol;
  const float* q2 = x2 + pb + gcol;
  const int gr0 = BH * by;
  const int ROWS = ((W - gr0) < (BH + 10)) ? (W - gr0) : (BH + 10);  // even
  const bool xtra = (bx * WB + WB + col) < W;

  float f1[11], f2[11], f3[11], f4[11];
#pragma unroll
  for (int j = 0; j < 11; ++j) { f1[j] = 0.f; f2[j] = 0.f; f3[j] = 0.f; f4[j] = 0.f; }

  float mse_acc = 0.f, ssim_acc = 0.f, cs_acc = 0.f;

#define LOADR(R, a, b, ae, be)                                          \
  {                                                                     \
    size_t ro = (size_t)(gr0 + (R)) * W;                                \
    a = q1[ro]; b = q2[ro];                                             \
    ae = 0.f; be = 0.f;                                                 \
    if (col < 12 && xtra) { ae = q1[ro + WB]; be = q2[ro + WB]; }       \
    if ((R) < BH) {                                                     \
      float d_ = a - b;                                                 \
      mse_acc = fmaf(d_, d_, mse_acc);                                  \
    }                                                                   \
  }

#define STAGE(R, a, b, ae, be)                                          \
  {                                                                     \
    const int sl_ = (R) & 3;                                            \
    vbuf[sl_][col] = (v2f){a, b};                                       \
    if (col < 12) vbuf[sl_][WB + col] = (v2f){ae, be};                  \
  }

#define PROW(R)                                                         \
  {                                                                     \
    const v2f* r_ = &vbuf[(R) & 3][col];                                \
    float s1 = 0.f, s2 = 0.f, s3 = 0.f, s4 = 0.f;                       \
    _Pragma("unroll") for (int k = 0; k < 11; ++k) {                    \
      v2f ab = r_[k];                                                   \
      float av = ab.x, bv = ab.y, w = gw.g[k];                          \
      float wa = w * av, wb = w * bv;                                   \
      s1 += wa; s2 += wb;                                               \
      s3 = fmaf(wa, bv, s3);                                            \
      s4 = fmaf(wa, av, s4);                                            \
      s4 = fmaf(wb, bv, s4);                                            \
    }                                                                   \
    _Pragma("unroll") for (int j = 10; j >= 1; --j) {                   \
      f1[j] = fmaf(gw.g[j], s1, f1[j - 1]);                             \
      f2[j] = fmaf(gw.g[j], s2, f2[j - 1]);                             \
      f3[j] = fmaf(gw.g[j], s3, f3[j - 1]);                             \
      f4[j] = fmaf(gw.g[j], s4, f4[j - 1]);                             \
    }                                                                   \
    f1[0] = gw.g[0] * s1;                                               \
    f2[0] = gw.g[0] * s2;                                               \
    f3[0] = gw.g[0] * s3;                                               \
    f4[0] = gw.g[0] * s4;                                               \
    if ((R) >= 10 && gcol < Ho) {                                       \
      float m1 = f1[10], m2 = f2[10], e12 = f3[10], esq = f4[10];       \
      float m12 = m1 * m2;                                              \
      float msq = fmaf(m1, m1, m2 * m2);                                \
      float v1 = 2.f * (e12 - m12) + C2F;                               \
      float vv2 = (esq - msq) + C2F;                                    \
      float csv = v1 * __builtin_amdgcn_rcpf(vv2);                      \
      cs_acc += csv;                                                    \
      ssim_acc += csv * (2.f * m12 + C1F) *                             \
                  __builtin_amdgcn_rcpf(msq + C1F);                     \
    }                                                                   \
  }

  {
    float a0, b0, ae0, be0, a1, b1, ae1, be1;
    LOADR(0, a0, b0, ae0, be0)
    LOADR(1, a1, b1, ae1, be1)
    STAGE(0, a0, b0, ae0, be0)
    STAGE(1, a1, b1, ae1, be1)
  }
  __syncthreads();

  for (int i = 0; i < ROWS / 2; ++i) {
    const int r0 = 2 * i, r1 = 2 * i + 1;
    const bool have = (r0 + 2) < ROWS;

    float na0 = 0.f, nb0 = 0.f, nae0 = 0.f, nbe0 = 0.f;
    float na1 = 0.f, nb1 = 0.f, nae1 = 0.f, nbe1 = 0.f;
    if (have) {
      LOADR(r0 + 2, na0, nb0, nae0, nbe0)
      LOADR(r1 + 2, na1, nb1, nae1, nbe1)
    }

    PROW(r0)
    PROW(r1)

    if (r0 < BH && col < (WB / 2)) {
      v2f x0 = vbuf[r0 & 3][2 * col], x1v = vbuf[r0 & 3][2 * col + 1];
      v2f y0 = vbuf[r1 & 3][2 * col], y1v = vbuf[r1 & 3][2 * col + 1];
      int orow = (gr0 >> 1) + i;
      size_t ob = (size_t)plane * W2 * W2 + (size_t)orow * W2 + bx * (WB / 2) + col;
      d1[ob] = 0.25f * ((x0.x + x1v.x) + (y0.x + y1v.x));
      d2[ob] = 0.25f * ((x0.y + x1v.y) + (y0.y + y1v.y));
    }

    if (have) {
      STAGE(r0 + 2, na0, nb0, nae0, nbe0)
      STAGE(r1 + 2, na1, nb1, nae1, nbe1)
      __syncthreads();
    }
  }
#undef LOADR
#undef STAGE
#undef PROW

#pragma unroll
  for (int off = 32; off; off >>= 1) {
    ssim_acc += __shfl_down(ssim_acc, off);
    cs_acc += __shfl_down(cs_acc, off);
    mse_acc += __shfl_down(mse_acc, off);
  }
  int wave = tid >> 6, lane = tid & 63;
  if (lane == 0) {
    red[0][wave] = ssim_acc;
    red[1][wave] = cs_acc;
    red[2][wave] = mse_acc;
  }
  __syncthreads();
  if (tid == 0) {
    float s = 0.f, cc = 0.f, m = 0.f;
#pragma unroll
    for (int i = 0; i < 4; ++i) { s += red[0][i]; cc += red[1][i]; m += red[2][i]; }
    int bi = (bz * gridDim.y + by) * gridDim.x + bx;
    partials[2 * bi] = s;
    partials[2 * bi + 1] = cc;
    msep[bi] = m;
  }
}

// ---------------------------------------------------------------------------
// ssim_level<LOGW,BH,PP>: R13 body; input pooled on-the-fly from A1 (256x256
// planes) with a (1<<PP)^2 mean. WB == W (single col strip; halo is zeros).
template <int LOGW, int BH, int PP>
__device__ __forceinline__ void ssim_level(
    char* ldsraw, float (*red)[4], int by, int bz,
    const float* __restrict__ x1, const float* __restrict__ x2,
    const GaussW& gw, float* __restrict__ partials, int bi)
{
  constexpr int W = 1 << LOGW;
  constexpr int Ho = W - 10;
  constexpr int WB = W;
  constexpr int P = 256 / WB;
  constexpr int STRIDE = WB + 12;
  constexpr int S = 1 << PP;
  constexpr float INV = 1.f / (float)(S * S);

  typedef v2f Slot[P][STRIDE];
  Slot* vbuf = (Slot*)ldsraw;   // [3] slots

  const int tid = threadIdx.x;
  const int p = tid >> LOGW;
  const int col = tid & (WB - 1);
  const int plane = bz * P + p;
  const int gr0 = BH * by;
  const int ROWS = ((W - gr0) < (BH + 10)) ? (W - gr0) : (BH + 10);

  const float* q1 = x1 + (size_t)plane * 65536;
  const float* q2 = x2 + (size_t)plane * 65536;

  float acc0[11], acc1[11], acc2[11], acc3[11], acc4[11];
#pragma unroll
  for (int j = 0; j < 11; ++j) {
    acc0[j] = 0.f; acc1[j] = 0.f; acc2[j] = 0.f; acc3[j] = 0.f; acc4[j] = 0.f;
  }

  float ssim_acc = 0.f, cs_acc = 0.f;

  // pooled load of virtual (row R, col `col`) from A1-resolution input
#define LOADV(R, a, b)                                                  \
  {                                                                     \
    const float* pa = q1 + (size_t)((gr0 + (R)) << PP) * 256 + (col << PP); \
    const float* pb = q2 + (size_t)((gr0 + (R)) << PP) * 256 + (col << PP); \
    float sa = 0.f, sb = 0.f;                                           \
    _Pragma("unroll 1") for (int i_ = 0; i_ < S; ++i_) {                \
      _Pragma("unroll") for (int j_ = 0; j_ < S; ++j_) {                \
        sa += pa[i_ * 256 + j_];                                        \
        sb += pb[i_ * 256 + j_];                                        \
      }                                                                 \
    }                                                                   \
    a = sa * INV; b = sb * INV;                                         \
  }

  // prologue: row 0 into slot 0 (halo cols = zeros)
  {
    float a, b;
    LOADV(0, a, b)
    vbuf[0][p][col] = (v2f){a, b};
    if (col < 12) vbuf[0][p][WB + col] = (v2f){0.f, 0.f};
  }
  __syncthreads();

  int cur = 0;
  for (int rr = 0; rr < ROWS; ++rr) {
    int nxt = cur + 1; if (nxt == 3) nxt = 0;
    const bool have = (rr + 1) < ROWS;

    float a = 0.f, b = 0.f;
    if (have) LOADV(rr + 1, a, b)

    const v2f* r = &vbuf[cur][p][col];
    float s1 = 0.f, s2 = 0.f, s11 = 0.f, s22 = 0.f, s12 = 0.f;
#pragma unroll
    for (int k = 0; k < 11; ++k) {
      v2f ab = r[k];
      float av = ab.x, bv = ab.y, w = gw.g[k];
      float wa = w * av, wb = w * bv;
      s1 += wa; s2 += wb;
      s11 = fmaf(wa, av, s11);
      s22 = fmaf(wb, bv, s22);
      s12 = fmaf(wa, bv, s12);
    }

#pragma unroll
    for (int j = 10; j >= 1; --j) {
      acc0[j] = fmaf(gw.g[j], s1, acc0[j - 1]);
      acc1[j] = fmaf(gw.g[j], s2, acc1[j - 1]);
      acc2[j] = fmaf(gw.g[j], s11, acc2[j - 1]);
      acc3[j] = fmaf(gw.g[j], s22, acc3[j - 1]);
      acc4[j] = fmaf(gw.g[j], s12, acc4[j - 1]);
    }
    acc0[0] = gw.g[0] * s1;
    acc1[0] = gw.g[0] * s2;
    acc2[0] = gw.g[0] * s11;
    acc3[0] = gw.g[0] * s22;
    acc4[0] = gw.g[0] * s12;

    if (rr >= 10 && col < Ho) {
      float m1 = acc0[10], m2 = acc1[10];
      float m1sq = m1 * m1, m2sq = m2 * m2, m12 = m1 * m2;
      float v1 = 2.f * (acc4[10] - m12) + C2F;
      float v2 = (acc2[10] - m1sq) + (acc3[10] - m2sq) + C2F;
      float csv = v1 * __builtin_amdgcn_rcpf(v2);
      cs_acc += csv;
      ssim_acc += csv * (2.f * m12 + C1F) *
                  __builtin_amdgcn_rcpf(m1sq + m2sq + C1F);
    }

    if (have) {
      vbuf[nxt][p][col] = (v2f){a, b};
      if (col < 12) vbuf[nxt][p][WB + col] = (v2f){0.f, 0.f};
      __syncthreads();
    }
    cur = nxt;
  }
#undef LOADV

#pragma unroll
  for (int off = 32; off; off >>= 1) {
    ssim_acc += __shfl_down(ssim_acc, off);
    cs_acc += __shfl_down(cs_acc, off);
  }
  int wave = tid >> 6, lane = tid & 63;
  if (lane == 0) {
    red[0][wave] = ssim_acc;
    red[1][wave] = cs_acc;
  }
  __syncthreads();
  if (tid == 0) {
    float s = 0.f, cc = 0.f;
#pragma unroll
    for (int i = 0; i < 4; ++i) { s += red[0][i]; cc += red[1][i]; }
    partials[2 * bi] = s;
    partials[2 * bi + 1] = cc;
  }
}

// ---------------------------------------------------------------------------
// K1: fused L1..L4. Block ranges: [0,768) L1, [768,1152) L2, [1152,1248) L3,
// [1248,1284) L4. All read only A1/B1.
__global__ __launch_bounds__(256, 4) void ssim_rest(
    const float* __restrict__ A1, const float* __restrict__ B1, GaussW gw,
    float* __restrict__ ws)
{
  __shared__ char lds[8448];   // max over levels (L4: 3*8*44*8)
  __shared__ float red[2][4];

  const int b = blockIdx.x;
  if (b < 768) {
    ssim_level<8, 16, 0>(lds, red, b & 15, b >> 4, A1, B1, gw, ws + P_L1, b);
  } else if (b < 1152) {
    const int i = b - 768;
    ssim_level<7, 8, 1>(lds, red, i & 15, i >> 4, A1, B1, gw, ws + P_L2, i);
  } else if (b < 1248) {
    const int i = b - 1152;
    ssim_level<6, 8, 2>(lds, red, i & 7, i >> 3, A1, B1, gw, ws + P_L3, i);
  } else {
    const int i = b - 1248;
    ssim_level<5, 4, 3>(lds, red, i % 6, i / 6, A1, B1, gw, ws + P_L4, i);
  }
}

// ---------------------------------------------------------------------------
__global__ __launch_bounds__(256) void final_kernel(
    const float* __restrict__ ws, float* __restrict__ out)
{
  __shared__ double sred[2][4];
  __shared__ double fin[11];  // ssim[5], cs[5], mse
  const int tid = threadIdx.x;
  const int offs[5] = {P_L0, P_L1, P_L2, P_L3, P_L4};
  const int cnts[5] = {1536, 768, 384, 96, 36};

  for (int l = 0; l < 5; ++l) {
    double s0 = 0.0, s1 = 0.0;
    for (int i = tid; i < cnts[l]; i += 256) {
      s0 += (double)ws[offs[l] + 2 * i];
      s1 += (double)ws[offs[l] + 2 * i + 1];
    }
#pragma unroll
    for (int off = 32; off; off >>= 1) {
      s0 += __shfl_down(s0, off);
      s1 += __shfl_down(s1, off);
    }
    if ((tid & 63) == 0) { sred[0][tid >> 6] = s0; sred[1][tid >> 6] = s1; }
    __syncthreads();
    if (tid == 0) {
      double aa = 0.0, bb = 0.0;
      for (int i = 0; i < 4; ++i) { aa += sred[0][i]; bb += sred[1][i]; }
      fin[l] = aa;
      fin[5 + l] = bb;
    }
    __syncthreads();
  }

  {
    double s0 = 0.0;
    for (int i = tid; i < 1536; i += 256) s0 += (double)ws[P_MSE + i];
#pragma unroll
    for (int off = 32; off; off >>= 1) s0 += __shfl_down(s0, off);
    if ((tid & 63) == 0) sred[0][tid >> 6] = s0;
    __syncthreads();
    if (tid == 0) {
      double aa = 0.0;
      for (int i = 0; i < 4; ++i) aa += sred[0][i];
      fin[10] = aa;
    }
    __syncthreads();
  }

  if (tid == 0) {
    const double wts[5] = {0.0448, 0.2856, 0.3001, 0.2363, 0.1333};
    const double dims[5] = {502.0, 246.0, 118.0, 54.0, 22.0};
    double mssim[5], mcs[5];
    for (int l = 0; l < 5; ++l) {
      double n = 48.0 * dims[l] * dims[l];
      mssim[l] = fin[l] / n;
      mcs[l] = fin[5 + l] / n;
    }
    // literal pytorch_msssim translation: prod(pow1[:-1] * pow2[-1])
    double p2last = pow(mssim[4], wts[4]);
    double prod = 1.0;
    for (int i = 0; i < 4; ++i) prod *= pow(mcs[i], wts[i]) * p2last;
    double msssim = prod;
    double mse = fin[10] / 12582912.0;
    out[0] = (float)(mse - msssim + 1.0);
    out[1] = (float)msssim;
  }
}

// ---------------------------------------------------------------------------
extern "C" void kernel_launch(void* const* d_in, const int* in_sizes, int n_in,
                              void* d_out, int out_size, void* d_ws, size_t ws_size,
                              hipStream_t stream)
{
  const float* rec = (const float*)d_in[0];   // reconst
  const float* orig = (const float*)d_in[1];  // original
  float* ws = (float*)d_ws;
  float* out = (float*)d_out;

  GaussW gw;
  {
    double g[11], s = 0.0;
    for (int i = 0; i < 11; ++i) {
      double x = (double)i - 5.0;
      g[i] = exp(-(x * x) / 4.5);
      s += g[i];
    }
    for (int i = 0; i < 11; ++i) gw.g[i] = (float)(g[i] / s);
  }

  float* A1 = ws + 0;
  float* B1 = ws + PYR2_OFF;

  // K0: L0 ssim + MSE + pool -> A1/B1
  ssim_l0<<<dim3(2, 16, 48), 256, 0, stream>>>(
      orig, rec, gw, ws + P_L0, ws + P_MSE, A1, B1);    // 1536 blocks

  // K1: fused L1..L4, all from A1/B1
  ssim_rest<<<dim3(1284), 256, 0, stream>>>(A1, B1, gw, ws);

  final_kernel<<<dim3(1), dim3(256), 0, stream>>>(ws, out);
}

// Round 20
// 145.050 us; speedup vs baseline: 3.7593x; 1.0435x over previous
//
#include <hip/hip_runtime.h>
#include <math.h>

// ---------------------------------------------------------------------------
// MS-SSIM + MSE loss, (16,3,512,512) f32, 5 pyramid levels.
// R20: measured-best piece per level.
//  L0   = R14/R19 body (86.0us proven): merged 4-field FIR, 2 rows/barrier,
//         4-slot v2f ring, MSE + pool fused. Grid (2,16,48).
//  L1-4 = R13 body (54.7us proven): 5-field FIR, 3-slot ring, per-row
//         barrier, pool fused, serial level chain. Grids 768/384/96/36.
// Register lore (R6/R11/R15/R17/R18): allocator caps this family at ~64
// VGPR; one FIR of state per thread max; launch_bounds stays (256,4).
// Spill tripwire: WRITE_SIZE@L0 ~25 MB.
// ---------------------------------------------------------------------------

#define NPLANES 48

struct GaussW { float g[11]; };

typedef float v2f __attribute__((ext_vector_type(2)));

// ws float offsets: pyramids + per-BLOCK partial areas (R13 layout)
#define PYR2_OFF  4177920
#define P_L0      8355840   // 1536 pairs
#define P_L1      8358912   // 768 pairs
#define P_L2      8360448   // 384 pairs
#define P_L3      8361216   // 96 pairs
#define P_L4      8361408   // 36 pairs
#define P_MSE     8361480   // 1536 singles

#define C1F 1.0e-4f
#define C2F 9.0e-4f

// ---------------------------------------------------------------------------
// L0 kernel (R14/R19 exact): W=512, BH=32, 256-col strips w/ halo.
__global__ __launch_bounds__(256, 4) void ssim_l0(
    const float* __restrict__ x1, const float* __restrict__ x2, GaussW gw,
    float* __restrict__ partials, float* __restrict__ msep,
    float* __restrict__ d1, float* __restrict__ d2)
{
  constexpr int W = 512, Ho = 502, BH = 32, WB = 256, STRIDE = WB + 12;
  constexpr int W2 = 256;

  __shared__ v2f vbuf[4][STRIDE];
  __shared__ float red[3][4];

  const int tid = threadIdx.x;
  const int col = tid;
  const int bx = blockIdx.x, by = blockIdx.y, bz = blockIdx.z;
  const int gcol = bx * WB + col;
  const int plane = bz;
  const size_t pb = (size_t)plane * W * W;
  const float* q1 = x1 + pb + gcol;
  const float* q2 = x2 + pb + gcol;
  const int gr0 = BH * by;
  const int ROWS = ((W - gr0) < (BH + 10)) ? (W - gr0) : (BH + 10);  // even
  const bool xtra = (bx * WB + WB + col) < W;

  float f1[11], f2[11], f3[11], f4[11];
#pragma unroll
  for (int j = 0; j < 11; ++j) { f1[j] = 0.f; f2[j] = 0.f; f3[j] = 0.f; f4[j] = 0.f; }

  float mse_acc = 0.f, ssim_acc = 0.f, cs_acc = 0.f;

#define LOADR(R, a, b, ae, be)                                          \
  {                                                                     \
    size_t ro = (size_t)(gr0 + (R)) * W;                                \
    a = q1[ro]; b = q2[ro];                                             \
    ae = 0.f; be = 0.f;                                                 \
    if (col < 12 && xtra) { ae = q1[ro + WB]; be = q2[ro + WB]; }       \
    if ((R) < BH) {                                                     \
      float d_ = a - b;                                                 \
      mse_acc = fmaf(d_, d_, mse_acc);                                  \
    }                                                                   \
  }

#define STAGE(R, a, b, ae, be)                                          \
  {                                                                     \
    const int sl_ = (R) & 3;                                            \
    vbuf[sl_][col] = (v2f){a, b};                                       \
    if (col < 12) vbuf[sl_][WB + col] = (v2f){ae, be};                  \
  }

#define PROW(R)                                                         \
  {                                                                     \
    const v2f* r_ = &vbuf[(R) & 3][col];                                \
    float s1 = 0.f, s2 = 0.f, s3 = 0.f, s4 = 0.f;                       \
    _Pragma("unroll") for (int k = 0; k < 11; ++k) {                    \
      v2f ab = r_[k];                                                   \
      float av = ab.x, bv = ab.y, w = gw.g[k];                          \
      float wa = w * av, wb = w * bv;                                   \
      s1 += wa; s2 += wb;                                               \
      s3 = fmaf(wa, bv, s3);                                            \
      s4 = fmaf(wa, av, s4);                                            \
      s4 = fmaf(wb, bv, s4);                                            \
    }                                                                   \
    _Pragma("unroll") for (int j = 10; j >= 1; --j) {                   \
      f1[j] = fmaf(gw.g[j], s1, f1[j - 1]);                             \
      f2[j] = fmaf(gw.g[j], s2, f2[j - 1]);                             \
      f3[j] = fmaf(gw.g[j], s3, f3[j - 1]);                             \
      f4[j] = fmaf(gw.g[j], s4, f4[j - 1]);                             \
    }                                                                   \
    f1[0] = gw.g[0] * s1;                                               \
    f2[0] = gw.g[0] * s2;                                               \
    f3[0] = gw.g[0] * s3;                                               \
    f4[0] = gw.g[0] * s4;                                               \
    if ((R) >= 10 && gcol < Ho) {                                       \
      float m1 = f1[10], m2 = f2[10], e12 = f3[10], esq = f4[10];       \
      float m12 = m1 * m2;                                              \
      float msq = fmaf(m1, m1, m2 * m2);                                \
      float v1 = 2.f * (e12 - m12) + C2F;                               \
      float vv2 = (esq - msq) + C2F;                                    \
      float csv = v1 * __builtin_amdgcn_rcpf(vv2);                      \
      cs_acc += csv;                                                    \
      ssim_acc += csv * (2.f * m12 + C1F) *                             \
                  __builtin_amdgcn_rcpf(msq + C1F);                     \
    }                                                                   \
  }

  {
    float a0, b0, ae0, be0, a1, b1, ae1, be1;
    LOADR(0, a0, b0, ae0, be0)
    LOADR(1, a1, b1, ae1, be1)
    STAGE(0, a0, b0, ae0, be0)
    STAGE(1, a1, b1, ae1, be1)
  }
  __syncthreads();

  for (int i = 0; i < ROWS / 2; ++i) {
    const int r0 = 2 * i, r1 = 2 * i + 1;
    const bool have = (r0 + 2) < ROWS;

    float na0 = 0.f, nb0 = 0.f, nae0 = 0.f, nbe0 = 0.f;
    float na1 = 0.f, nb1 = 0.f, nae1 = 0.f, nbe1 = 0.f;
    if (have) {
      LOADR(r0 + 2, na0, nb0, nae0, nbe0)
      LOADR(r1 + 2, na1, nb1, nae1, nbe1)
    }

    PROW(r0)
    PROW(r1)

    if (r0 < BH && col < (WB / 2)) {
      v2f x0 = vbuf[r0 & 3][2 * col], x1v = vbuf[r0 & 3][2 * col + 1];
      v2f y0 = vbuf[r1 & 3][2 * col], y1v = vbuf[r1 & 3][2 * col + 1];
      int orow = (gr0 >> 1) + i;
      size_t ob = (size_t)plane * W2 * W2 + (size_t)orow * W2 + bx * (WB / 2) + col;
      d1[ob] = 0.25f * ((x0.x + x1v.x) + (y0.x + y1v.x));
      d2[ob] = 0.25f * ((x0.y + x1v.y) + (y0.y + y1v.y));
    }

    if (have) {
      STAGE(r0 + 2, na0, nb0, nae0, nbe0)
      STAGE(r1 + 2, na1, nb1, nae1, nbe1)
      __syncthreads();
    }
  }
#undef LOADR
#undef STAGE
#undef PROW

#pragma unroll
  for (int off = 32; off; off >>= 1) {
    ssim_acc += __shfl_down(ssim_acc, off);
    cs_acc += __shfl_down(cs_acc, off);
    mse_acc += __shfl_down(mse_acc, off);
  }
  int wave = tid >> 6, lane = tid & 63;
  if (lane == 0) {
    red[0][wave] = ssim_acc;
    red[1][wave] = cs_acc;
    red[2][wave] = mse_acc;
  }
  __syncthreads();
  if (tid == 0) {
    float s = 0.f, cc = 0.f, m = 0.f;
#pragma unroll
    for (int i = 0; i < 4; ++i) { s += red[0][i]; cc += red[1][i]; m += red[2][i]; }
    int bi = (bz * gridDim.y + by) * gridDim.x + bx;
    partials[2 * bi] = s;
    partials[2 * bi + 1] = cc;
    msep[bi] = m;
  }
}

// ---------------------------------------------------------------------------
// R13's proven kernel for L1..L4 (5-field FIR, 3-slot ring, per-row barrier).
template <int LOGW, int BH, int DO_POOL>
__global__ __launch_bounds__(256, 4) void ssim_band(
    const float* __restrict__ x1, const float* __restrict__ x2, GaussW gw,
    float* __restrict__ partials,
    float* __restrict__ d1, float* __restrict__ d2)
{
  constexpr int W = 1 << LOGW;
  constexpr int Ho = W - 10;
  constexpr int LOGWB = (LOGW > 8) ? 8 : LOGW;
  constexpr int WB = 1 << LOGWB;
  constexpr int P = 256 >> LOGWB;
  constexpr int STRIDE = WB + 12;
  constexpr int W2 = W >> 1;

  __shared__ v2f vbuf[3][P][STRIDE];
  __shared__ float red[2][4];

  const int tid = threadIdx.x;
  const int p = tid >> LOGWB;
  const int col = tid & (WB - 1);
  const int bx = blockIdx.x, by = blockIdx.y, bz = blockIdx.z;
  const int gcol = bx * WB + col;
  const int plane = bz * P + p;
  const size_t pb = (size_t)plane * W * W;
  const float* q1 = x1 + pb + gcol;
  const float* q2 = x2 + pb + gcol;
  const int gr0 = BH * by;
  const int ROWS = ((W - gr0) < (BH + 10)) ? (W - gr0) : (BH + 10);
  const bool xtra = (bx * WB + WB + col) < W;

  float acc0[11], acc1[11], acc2[11], acc3[11], acc4[11];
#pragma unroll
  for (int j = 0; j < 11; ++j) {
    acc0[j] = 0.f; acc1[j] = 0.f; acc2[j] = 0.f; acc3[j] = 0.f; acc4[j] = 0.f;
  }

  float ssim_acc = 0.f, cs_acc = 0.f;

  {
    size_t ro = (size_t)gr0 * W;
    float a = q1[ro], b = q2[ro];
    float ae = 0.f, be = 0.f;
    if (col < 12 && xtra) { ae = q1[ro + WB]; be = q2[ro + WB]; }
    vbuf[0][p][col] = (v2f){a, b};
    if (col < 12) vbuf[0][p][WB + col] = (v2f){ae, be};
  }
  __syncthreads();

  int cur = 0;
  for (int rr = 0; rr < ROWS; ++rr) {
    int nxt = cur + 1; if (nxt == 3) nxt = 0;
    int prv = cur - 1; if (prv < 0) prv = 2;
    const bool have = (rr + 1) < ROWS;

    float a = 0.f, b = 0.f, ae = 0.f, be = 0.f;
    if (have) {
      size_t ro = (size_t)(gr0 + rr + 1) * W;
      a = q1[ro]; b = q2[ro];
      if (col < 12 && xtra) { ae = q1[ro + WB]; be = q2[ro + WB]; }
    }

    const v2f* r = &vbuf[cur][p][col];
    float s1 = 0.f, s2 = 0.f, s11 = 0.f, s22 = 0.f, s12 = 0.f;
#pragma unroll
    for (int k = 0; k < 11; ++k) {
      v2f ab = r[k];
      float av = ab.x, bv = ab.y, w = gw.g[k];
      float wa = w * av, wb = w * bv;
      s1 += wa; s2 += wb;
      s11 = fmaf(wa, av, s11);
      s22 = fmaf(wb, bv, s22);
      s12 = fmaf(wa, bv, s12);
    }

#pragma unroll
    for (int j = 10; j >= 1; --j) {
      acc0[j] = fmaf(gw.g[j], s1, acc0[j - 1]);
      acc1[j] = fmaf(gw.g[j], s2, acc1[j - 1]);
      acc2[j] = fmaf(gw.g[j], s11, acc2[j - 1]);
      acc3[j] = fmaf(gw.g[j], s22, acc3[j - 1]);
      acc4[j] = fmaf(gw.g[j], s12, acc4[j - 1]);
    }
    acc0[0] = gw.g[0] * s1;
    acc1[0] = gw.g[0] * s2;
    acc2[0] = gw.g[0] * s11;
    acc3[0] = gw.g[0] * s22;
    acc4[0] = gw.g[0] * s12;

    if (rr >= 10 && gcol < Ho) {
      float m1 = acc0[10], m2 = acc1[10];
      float m1sq = m1 * m1, m2sq = m2 * m2, m12 = m1 * m2;
      float v1 = 2.f * (acc4[10] - m12) + C2F;
      float v2 = (acc2[10] - m1sq) + (acc3[10] - m2sq) + C2F;
      float csv = v1 * __builtin_amdgcn_rcpf(v2);
      cs_acc += csv;
      ssim_acc += csv * (2.f * m12 + C1F) *
                  __builtin_amdgcn_rcpf(m1sq + m2sq + C1F);
    }

    if (DO_POOL && (rr & 1) && rr < BH && col < (WB / 2)) {
      v2f x0 = vbuf[prv][p][2 * col], x1v = vbuf[prv][p][2 * col + 1];
      v2f y0 = vbuf[cur][p][2 * col], y1v = vbuf[cur][p][2 * col + 1];
      int orow = (gr0 >> 1) + (rr >> 1);
      size_t ob = (size_t)plane * W2 * W2 + (size_t)orow * W2 + bx * (WB / 2) + col;
      d1[ob] = 0.25f * ((x0.x + x1v.x) + (y0.x + y1v.x));
      d2[ob] = 0.25f * ((x0.y + x1v.y) + (y0.y + y1v.y));
    }

    if (have) {
      vbuf[nxt][p][col] = (v2f){a, b};
      if (col < 12) vbuf[nxt][p][WB + col] = (v2f){ae, be};
      __syncthreads();
    }
    cur = nxt;
  }

#pragma unroll
  for (int off = 32; off; off >>= 1) {
    ssim_acc += __shfl_down(ssim_acc, off);
    cs_acc += __shfl_down(cs_acc, off);
  }
  int wave = tid >> 6, lane = tid & 63;
  if (lane == 0) {
    red[0][wave] = ssim_acc;
    red[1][wave] = cs_acc;
  }
  __syncthreads();
  if (tid == 0) {
    float s = 0.f, cc = 0.f;
#pragma unroll
    for (int i = 0; i < 4; ++i) { s += red[0][i]; cc += red[1][i]; }
    int bi = (bz * gridDim.y + by) * gridDim.x + bx;
    partials[2 * bi] = s;
    partials[2 * bi + 1] = cc;
  }
}

// ---------------------------------------------------------------------------
__global__ __launch_bounds__(256) void final_kernel(
    const float* __restrict__ ws, float* __restrict__ out)
{
  __shared__ double sred[2][4];
  __shared__ double fin[11];  // ssim[5], cs[5], mse
  const int tid = threadIdx.x;
  const int offs[5] = {P_L0, P_L1, P_L2, P_L3, P_L4};
  const int cnts[5] = {1536, 768, 384, 96, 36};

  for (int l = 0; l < 5; ++l) {
    double s0 = 0.0, s1 = 0.0;
    for (int i = tid; i < cnts[l]; i += 256) {
      s0 += (double)ws[offs[l] + 2 * i];
      s1 += (double)ws[offs[l] + 2 * i + 1];
    }
#pragma unroll
    for (int off = 32; off; off >>= 1) {
      s0 += __shfl_down(s0, off);
      s1 += __shfl_down(s1, off);
    }
    if ((tid & 63) == 0) { sred[0][tid >> 6] = s0; sred[1][tid >> 6] = s1; }
    __syncthreads();
    if (tid == 0) {
      double aa = 0.0, bb = 0.0;
      for (int i = 0; i < 4; ++i) { aa += sred[0][i]; bb += sred[1][i]; }
      fin[l] = aa;
      fin[5 + l] = bb;
    }
    __syncthreads();
  }

  {
    double s0 = 0.0;
    for (int i = tid; i < 1536; i += 256) s0 += (double)ws[P_MSE + i];
#pragma unroll
    for (int off = 32; off; off >>= 1) s0 += __shfl_down(s0, off);
    if ((tid & 63) == 0) sred[0][tid >> 6] = s0;
    __syncthreads();
    if (tid == 0) {
      double aa = 0.0;
      for (int i = 0; i < 4; ++i) aa += sred[0][i];
      fin[10] = aa;
    }
    __syncthreads();
  }

  if (tid == 0) {
    const double wts[5] = {0.0448, 0.2856, 0.3001, 0.2363, 0.1333};
    const double dims[5] = {502.0, 246.0, 118.0, 54.0, 22.0};
    double mssim[5], mcs[5];
    for (int l = 0; l < 5; ++l) {
      double n = 48.0 * dims[l] * dims[l];
      mssim[l] = fin[l] / n;
      mcs[l] = fin[5 + l] / n;
    }
    // literal pytorch_msssim translation: prod(pow1[:-1] * pow2[-1])
    double p2last = pow(mssim[4], wts[4]);
    double prod = 1.0;
    for (int i = 0; i < 4; ++i) prod *= pow(mcs[i], wts[i]) * p2last;
    double msssim = prod;
    double mse = fin[10] / 12582912.0;
    out[0] = (float)(mse - msssim + 1.0);
    out[1] = (float)msssim;
  }
}

// ---------------------------------------------------------------------------
extern "C" void kernel_launch(void* const* d_in, const int* in_sizes, int n_in,
                              void* d_out, int out_size, void* d_ws, size_t ws_size,
                              hipStream_t stream)
{
  const float* rec = (const float*)d_in[0];   // reconst
  const float* orig = (const float*)d_in[1];  // original
  float* ws = (float*)d_ws;
  float* out = (float*)d_out;

  GaussW gw;
  {
    double g[11], s = 0.0;
    for (int i = 0; i < 11; ++i) {
      double x = (double)i - 5.0;
      g[i] = exp(-(x * x) / 4.5);
      s += g[i];
    }
    for (int i = 0; i < 11; ++i) gw.g[i] = (float)(g[i] / s);
  }

  // pyramid pointers
  float* A1 = ws + 0;
  float* A2 = ws + 3145728;
  float* A3 = ws + 3932160;
  float* A4 = ws + 4128768;
  float* B1 = ws + PYR2_OFF;
  float* B2 = ws + PYR2_OFF + 3145728;
  float* B3 = ws + PYR2_OFF + 3932160;
  float* B4 = ws + PYR2_OFF + 4128768;

  // L0: R14/R19 proven kernel
  ssim_l0<<<dim3(2, 16, 48), 256, 0, stream>>>(
      orig, rec, gw, ws + P_L0, ws + P_MSE, A1, B1);    // 1536 blocks

  // L1..L4: R13's proven kernel + grids
  ssim_band<8, 16, 1><<<dim3(1, 16, 48), 256, 0, stream>>>(
      A1, B1, gw, ws + P_L1, A2, B2);                   // 768 blocks
  ssim_band<7, 8, 1><<<dim3(1, 16, 24), 256, 0, stream>>>(
      A2, B2, gw, ws + P_L2, A3, B3);                   // 384 blocks
  ssim_band<6, 8, 1><<<dim3(1, 8, 12), 256, 0, stream>>>(
      A3, B3, gw, ws + P_L3, A4, B4);                   // 96 blocks
  ssim_band<5, 4, 0><<<dim3(1, 6, 6), 256, 0, stream>>>(
      A4, B4, gw, ws + P_L4, nullptr, nullptr);         // 36 blocks

  final_kernel<<<dim3(1), dim3(256), 0, stream>>>(ws, out);
}